// Round 1
// baseline (3411.740 us; speedup 1.0000x reference)
//
#include <hip/hip_runtime.h>

#define NS 32
#define NV 8
#define HID 96
#define WNUM 1664
#define NA_DIM 56
#define OUT_DIM 80
#define EPB 16
#define JCHUNK 256
#define KSLICE 32

#define N0 0.158113883f       // 1/sqrt(40)
#define INV_S3 0.5773502692f  // 1/sqrt(3)
#define C_OUT1E 0.25f         // (1/sqrt(2)) * (1/sqrt(8))

__global__ __launch_bounds__(256) void zero_kernel(float* __restrict__ p, int n) {
  int i = blockIdx.x * 256 + threadIdx.x;
  if (i < n) p[i] = 0.f;
}

// K1: h = relu(edge_attr @ W1 + b1), 32 edges/block
__global__ __launch_bounds__(256) void gemm1_kernel(
    const float* __restrict__ A, const float* __restrict__ W1,
    const float* __restrict__ b1, float* __restrict__ h)
{
  __shared__ float as_[32][HID + 4];
  __shared__ float w1s[HID][HID];
  const int tid = threadIdx.x;
  const int e0 = blockIdx.x * 32;

  for (int idx = tid; idx < 32 * HID; idx += 256) {
    int e = idx / HID, k = idx % HID;
    as_[e][k] = A[(e0 + e) * HID + k];
  }
  for (int idx = tid; idx < HID * HID; idx += 256)
    ((float*)w1s)[idx] = W1[idx];
  __syncthreads();

  const int jl = tid & 31;
  const int el = tid >> 5;  // 0..7
  const float bb0 = b1[jl], bb1 = b1[32 + jl], bb2 = b1[64 + jl];
  for (int ep = 0; ep < 4; ++ep) {
    int e = ep * 8 + el;
    float a0 = bb0, a1 = bb1, a2 = bb2;
    #pragma unroll
    for (int k = 0; k < HID; ++k) {
      float va = as_[e][k];
      a0 = fmaf(va, w1s[k][jl], a0);
      a1 = fmaf(va, w1s[k][32 + jl], a1);
      a2 = fmaf(va, w1s[k][64 + jl], a2);
    }
    int row = (e0 + e) * HID;
    h[row + jl]      = fmaxf(a0, 0.f);
    h[row + 32 + jl] = fmaxf(a1, 0.f);
    h[row + 64 + jl] = fmaxf(a2, 0.f);
  }
}

// K2: fused  w = h@W2+b2  -> tensor product -> atomic scatter into out
// 16 edges/block, 256 threads. w computed in 7 chunks of 256 columns.
__global__ __launch_bounds__(256) void fused_kernel(
    const float* __restrict__ h, const float* __restrict__ W2,
    const float* __restrict__ b2, const float* __restrict__ node_attr,
    const float* __restrict__ edge_sh, const int* __restrict__ edge_src,
    const int* __restrict__ edge_dst, float* __restrict__ out,
    float* __restrict__ cnt)
{
  __shared__ __align__(16) float hs[HID][EPB + 4];    // h transposed (e contiguous)
  __shared__ __align__(16) float w2s[KSLICE][JCHUNK]; // W2 k-slice
  __shared__ __align__(16) float ws[EPB][JCHUNK];     // w chunk
  __shared__ float x0s[EPB][NS];
  __shared__ float x1s[EPB][NV][3];
  __shared__ float sh1s[EPB][3];
  __shared__ float s0s[EPB];
  __shared__ float dsu[EPB][NV];     // x1[u] . sh1
  __shared__ float crs[EPB][NV][3];  // cross(x1[u], sh1)
  __shared__ int   srcs[EPB];
  __shared__ int   dsts[EPB];

  const int tid = threadIdx.x;
  const int e0 = blockIdx.x * EPB;

  if (tid < EPB) {
    srcs[tid] = edge_src[e0 + tid];
    dsts[tid] = edge_dst[e0 + tid];
    s0s[tid] = edge_sh[(e0 + tid) * 4 + 0];
  }
  if (tid >= 64 && tid < 64 + EPB * 3) {
    int i = tid - 64;
    int e = i / 3, m = i % 3;
    sh1s[e][m] = edge_sh[(e0 + e) * 4 + 1 + m];
  }
  __syncthreads();  // dsts ready

  // gather node attrs of edge_dst
  for (int idx = tid; idx < EPB * NA_DIM; idx += 256) {
    int e = idx / NA_DIM, c = idx % NA_DIM;
    float v = node_attr[dsts[e] * NA_DIM + c];
    if (c < NS) x0s[e][c] = v;
    else { int q = c - NS; x1s[e][q / 3][q % 3] = v; }
  }
  // stage h transposed
  for (int idx = tid; idx < EPB * HID; idx += 256) {
    int e = idx / HID, k = idx % HID;
    hs[k][e] = h[(e0 + e) * HID + k];
  }
  __syncthreads();

  // derived per-edge quantities
  if (tid < EPB * NV) {
    int e = tid / NV, u = tid % NV;
    float a0 = x1s[e][u][0], a1 = x1s[e][u][1], a2 = x1s[e][u][2];
    float b0 = sh1s[e][0], b1v = sh1s[e][1], b2v = sh1s[e][2];
    dsu[e][u] = a0 * b0 + a1 * b1v + a2 * b2v;
    crs[e][u][0] = a1 * b2v - a2 * b1v;
    crs[e][u][1] = a2 * b0 - a0 * b2v;
    crs[e][u][2] = a0 * b1v - a1 * b0;
  }
  if (tid < EPB) atomicAdd(&cnt[srcs[tid]], 1.0f);

  float oacc[5];
  #pragma unroll
  for (int p = 0; p < 5; ++p) oacc[p] = 0.f;

  const int eg = tid >> 6;  // 0..3 -> edges eg*4..eg*4+3
  const int jg = tid & 63;  // float4-column group
  __syncthreads();

  for (int chunk = 0; chunk < 7; ++chunk) {
    const int jlo = chunk * JCHUNK;
    float facc[4][4];
    #pragma unroll
    for (int i = 0; i < 4; ++i)
      #pragma unroll
      for (int j = 0; j < 4; ++j) facc[i][j] = 0.f;

    #pragma unroll
    for (int ks = 0; ks < 3; ++ks) {
      const int k0 = ks * KSLICE;
      __syncthreads();  // prev users of w2s / ws done
      #pragma unroll
      for (int t = 0; t < 8; ++t) {
        int idx = tid + t * 256;          // 0..2047
        int r = idx >> 6, c4 = idx & 63;  // 32 rows x 64 float4
        int j = jlo + c4 * 4;
        float4 v = make_float4(0.f, 0.f, 0.f, 0.f);
        if (j < WNUM) v = *(const float4*)&W2[(k0 + r) * WNUM + j];
        *(float4*)&w2s[r][c4 * 4] = v;
      }
      __syncthreads();
      #pragma unroll
      for (int k = 0; k < KSLICE; ++k) {
        const float4 hv = *(const float4*)&hs[k0 + k][eg * 4];
        const float4 wv = *(const float4*)&w2s[k][jg * 4];
        const float hvv[4] = {hv.x, hv.y, hv.z, hv.w};
        const float wvv[4] = {wv.x, wv.y, wv.z, wv.w};
        #pragma unroll
        for (int i = 0; i < 4; ++i)
          #pragma unroll
          for (int j = 0; j < 4; ++j)
            facc[i][j] = fmaf(hvv[i], wvv[j], facc[i][j]);
      }
    }

    // write w chunk (+bias) to LDS
    {
      const int j = jlo + jg * 4;
      if (j < WNUM) {
        const float4 bb = *(const float4*)&b2[j];
        #pragma unroll
        for (int i = 0; i < 4; ++i) {
          float4 o4;
          o4.x = facc[i][0] + bb.x; o4.y = facc[i][1] + bb.y;
          o4.z = facc[i][2] + bb.z; o4.w = facc[i][3] + bb.w;
          *(float4*)&ws[eg * 4 + i][jg * 4] = o4;
        }
      }
    }
    __syncthreads();

    // ---- TP accumulation for this chunk ----
    // chunk 0..3: w1 rows u=chunk*8..+7 ; chunk 4: all of w2 ;
    // chunk 5: w3 (off 0..63) + w4 u=0..5 (off 64..255) ;
    // chunk 6: w4 u=6,7 (off 0..63) + w5 (off 64..127)
    if (chunk < 4) {
      const int u0 = chunk * 8;
      #pragma unroll
      for (int p = 0; p < 5; ++p) {
        const int idx = p * 256 + tid;
        const int e = idx / OUT_DIM, o = idx % OUT_DIM;
        if (o < NS) {
          float t = 0.f;
          #pragma unroll
          for (int uu = 0; uu < 8; ++uu)
            t = fmaf(x0s[e][u0 + uu], ws[e][uu * NS + o], t);
          oacc[p] = fmaf(t, s0s[e], oacc[p]);
        }
      }
    } else if (chunk == 4) {
      #pragma unroll
      for (int p = 0; p < 5; ++p) {
        const int idx = p * 256 + tid;
        const int e = idx / OUT_DIM, o = idx % OUT_DIM;
        if (o >= NS && o < NS + 24) {
          const int vv = o - NS, v = vv / 3, m = vv % 3;
          float t = 0.f;
          #pragma unroll
          for (int u = 0; u < NS; ++u)
            t = fmaf(x0s[e][u], ws[e][u * NV + v], t);
          oacc[p] = fmaf(t, sh1s[e][m], oacc[p]);
        }
      }
    } else if (chunk == 5) {
      #pragma unroll
      for (int p = 0; p < 5; ++p) {
        const int idx = p * 256 + tid;
        const int e = idx / OUT_DIM, o = idx % OUT_DIM;
        if (o < NS) {
          float t = 0.f;
          #pragma unroll
          for (int u = 0; u < 6; ++u)
            t = fmaf(dsu[e][u], ws[e][64 + u * NS + o], t);
          oacc[p] = fmaf(t, INV_S3, oacc[p]);
        } else if (o < NS + 24) {
          const int vv = o - NS, v = vv / 3, m = vv % 3;
          float t = 0.f;
          #pragma unroll
          for (int u = 0; u < NV; ++u)
            t = fmaf(x1s[e][u][m], ws[e][u * NV + v], t);
          oacc[p] = fmaf(t, s0s[e], oacc[p]);
        }
      }
    } else {
      #pragma unroll
      for (int p = 0; p < 5; ++p) {
        const int idx = p * 256 + tid;
        const int e = idx / OUT_DIM, o = idx % OUT_DIM;
        if (o < NS) {
          float t = dsu[e][6] * ws[e][o];
          t = fmaf(dsu[e][7], ws[e][NS + o], t);
          oacc[p] = fmaf(t, INV_S3, oacc[p]);
        } else if (o >= NS + 24) {
          const int vv = o - (NS + 24), v = vv / 3, m = vv % 3;
          float t = 0.f;
          #pragma unroll
          for (int u = 0; u < NV; ++u)
            t = fmaf(crs[e][u][m], ws[e][64 + u * NV + v], t);
          oacc[p] += t;  // *0.25 folded at the end
        }
      }
    }
  }

  // scatter with final normalization
  #pragma unroll
  for (int p = 0; p < 5; ++p) {
    const int idx = p * 256 + tid;
    const int e = idx / OUT_DIM, o = idx % OUT_DIM;
    const float scale = (o < NS + 24) ? N0 : C_OUT1E;
    atomicAdd(&out[srcs[e] * OUT_DIM + o], oacc[p] * scale);
  }
}

// K3: divide by count
__global__ __launch_bounds__(256) void div_kernel(
    float* __restrict__ out, const float* __restrict__ cnt, int n)
{
  int idx = blockIdx.x * 256 + threadIdx.x;
  if (idx < n) {
    float c = cnt[idx / OUT_DIM];
    out[idx] = out[idx] / fmaxf(c, 1.0f);
  }
}

extern "C" void kernel_launch(void* const* d_in, const int* in_sizes, int n_in,
                              void* d_out, int out_size, void* d_ws, size_t ws_size,
                              hipStream_t stream) {
  const float* node_attr = (const float*)d_in[0];
  const float* edge_attr = (const float*)d_in[1];
  const float* edge_sh   = (const float*)d_in[2];
  const float* W1        = (const float*)d_in[3];
  const float* b1        = (const float*)d_in[4];
  const float* W2        = (const float*)d_in[5];
  const float* b2        = (const float*)d_in[6];
  const int*   edge_src  = (const int*)d_in[7];
  const int*   edge_dst  = (const int*)d_in[8];
  float* out = (float*)d_out;

  const int E = in_sizes[7];
  const int N = in_sizes[0] / NA_DIM;

  float* cnt = (float*)d_ws;
  float* h   = (float*)((char*)d_ws + (1 << 20));  // 46 MB for h

  zero_kernel<<<(N * OUT_DIM + 255) / 256, 256, 0, stream>>>(out, N * OUT_DIM);
  zero_kernel<<<(N + 255) / 256, 256, 0, stream>>>(cnt, N);
  gemm1_kernel<<<E / 32, 256, 0, stream>>>(edge_attr, W1, b1, h);
  fused_kernel<<<E / EPB, 256, 0, stream>>>(h, W2, b2, node_attr, edge_sh,
                                            edge_src, edge_dst, out, cnt);
  div_kernel<<<(N * OUT_DIM + 255) / 256, 256, 0, stream>>>(out, cnt, N * OUT_DIM);
}

// Round 2
// 446.465 us; speedup vs baseline: 7.6417x; 7.6417x over previous
//
#include <hip/hip_runtime.h>

typedef short short8 __attribute__((ext_vector_type(8)));
typedef float f32x4 __attribute__((ext_vector_type(4)));
typedef unsigned short ushort4v __attribute__((ext_vector_type(4)));

#define HID 96
#define WNUM 1664
#define NA_DIM 56
#define OUT_DIM 80
#define EPB 64
#define NT_TOT 104   // 1664/16
#define CHW 208      // cols per chunk
#define NCH 8
#define NTC 13       // n-tiles per chunk

#define N0f 0.158113883f      // 1/sqrt(40)
#define INV_S3 0.5773502692f  // 1/sqrt(3)
#define C_OUT1E 0.25f         // (1/sqrt(2))*(1/sqrt(8))

__device__ __forceinline__ unsigned short f2bf(float x) {
  unsigned u = __builtin_bit_cast(unsigned, x);
  u += 0x7FFFu + ((u >> 16) & 1u);
  return (unsigned short)(u >> 16);
}
__device__ __forceinline__ float bf2f(unsigned short x) {
  unsigned u = ((unsigned)x) << 16;
  return __builtin_bit_cast(float, u);
}

// column permutation: new col J -> original W2 col
__device__ __forceinline__ int perm_col(int J) {
  int c = J / CHW, l = J - (J / CHW) * CHW;
  if (l < 128) { int vp = l >> 5, u = l & 31; return u * 32 + 4 * c + vp; }          // w1
  if (l < 160) { int u = l - 128; return 1024 + u * 8 + c; }                          // w2
  if (l < 168) { int u = l - 160; return 1280 + u * 8 + c; }                          // w3
  if (l < 200) { int q = l - 168; int vp = q >> 3, u = q & 7; return 1344 + u * 32 + 4 * c + vp; } // w4
  { int u = l - 200; return 1600 + u * 8 + c; }                                       // w5
}

__global__ __launch_bounds__(256) void zero_kernel(float* __restrict__ p, int n) {
  int i = blockIdx.x * 256 + threadIdx.x;
  if (i < n) p[i] = 0.f;
}

// pack W2 (permuted) and W1 into MFMA B-fragment layout (bf16); permute b2
__global__ __launch_bounds__(256) void prep_kernel(
    const float* __restrict__ W2, const float* __restrict__ W1,
    const float* __restrict__ b2, unsigned short* __restrict__ W2p,
    unsigned short* __restrict__ W1p, float* __restrict__ b2p)
{
  int gid = blockIdx.x * 256 + threadIdx.x;
  const int NW2 = NT_TOT * 3 * 64;
  const int NW1 = 18 * 64;
  if (gid < NW2) {
    int tile = gid >> 6, ln = gid & 63;
    int nt = tile / 3, s = tile - nt * 3;
    int J = nt * 16 + (ln & 15);
    int jo = perm_col(J);
    int kbase = s * 32 + ((ln >> 4) << 3);
    #pragma unroll
    for (int j = 0; j < 8; ++j)
      W2p[(size_t)gid * 8 + j] = f2bf(W2[(kbase + j) * WNUM + jo]);
  } else if (gid < NW2 + NW1) {
    int g = gid - NW2;
    int tile = g >> 6, ln = g & 63;
    int nt = tile / 3, s = tile - nt * 3;
    int col = nt * 16 + (ln & 15);
    int kbase = s * 32 + ((ln >> 4) << 3);
    #pragma unroll
    for (int j = 0; j < 8; ++j)
      W1p[(size_t)g * 8 + j] = f2bf(W1[(kbase + j) * HID + col]);
  } else if (gid < NW2 + NW1 + WNUM) {
    int J = gid - (NW2 + NW1);
    b2p[J] = b2[perm_col(J)];
  }
}

// K1: h = relu(edge_attr @ W1 + b1) in bf16 via MFMA. 64 edges/block, 4 waves.
__global__ __launch_bounds__(256) void gemm1_mfma(
    const float* __restrict__ A, const unsigned short* __restrict__ W1p,
    const float* __restrict__ b1, unsigned short* __restrict__ h)
{
  const int tid = threadIdx.x, ln = tid & 63, wv = tid >> 6;
  const int e0 = blockIdx.x * 64;
  const int row = e0 + wv * 16 + (ln & 15);
  short8 af[3];
  #pragma unroll
  for (int s = 0; s < 3; ++s) {
    const float* p = A + (size_t)row * HID + s * 32 + ((ln >> 4) << 3);
    short8 v;
    #pragma unroll
    for (int j = 0; j < 8; ++j) v[j] = (short)f2bf(p[j]);
    af[s] = v;
  }
  #pragma unroll
  for (int nt = 0; nt < 6; ++nt) {
    f32x4 acc = {0.f, 0.f, 0.f, 0.f};
    #pragma unroll
    for (int s = 0; s < 3; ++s) {
      short8 bfr = *(const short8*)(W1p + ((size_t)(nt * 3 + s) * 64 + ln) * 8);
      acc = __builtin_amdgcn_mfma_f32_16x16x32_bf16(af[s], bfr, acc, 0, 0, 0);
    }
    int col = nt * 16 + (ln & 15);
    float bb = b1[col];
    #pragma unroll
    for (int r = 0; r < 4; ++r) {
      float v = fmaxf(acc[r] + bb, 0.f);
      int er = e0 + wv * 16 + ((ln >> 4) << 2) + r;
      h[(size_t)er * HID + col] = f2bf(v);
    }
  }
}

// K2: fused  w = h@W2+b2 (MFMA, chunked) -> tensor product -> atomic scatter
__global__ __launch_bounds__(512, 4) void fused_mfma(
    const unsigned short* __restrict__ h, const unsigned short* __restrict__ W2p,
    const float* __restrict__ b2p, const float* __restrict__ node_attr,
    const float* __restrict__ edge_sh, const int* __restrict__ edge_src,
    const int* __restrict__ edge_dst, float* __restrict__ out,
    float* __restrict__ cnt)
{
  __shared__ unsigned short ws[EPB][212];   // w chunk, bf16, swizzled region0
  __shared__ float x0s[EPB][32];
  __shared__ float x1s[EPB][3][8];
  __shared__ float crs[EPB][3][8];
  __shared__ float dsu[EPB][8];
  __shared__ float sh1s[EPB][3];
  __shared__ float s0s[EPB];
  __shared__ int   srcs[EPB];
  __shared__ int   dsts[EPB];
  __shared__ float bch[CHW];

  const int tid = threadIdx.x;
  const int e0 = blockIdx.x * EPB;

  if (tid < EPB) {
    srcs[tid] = edge_src[e0 + tid];
    dsts[tid] = edge_dst[e0 + tid];
    s0s[tid] = edge_sh[(size_t)(e0 + tid) * 4];
  }
  if (tid >= 128 && tid < 128 + EPB * 3) {
    int i = tid - 128, e = i / 3, m = i - e * 3;
    sh1s[e][m] = edge_sh[(size_t)(e0 + e) * 4 + 1 + m];
  }
  if (tid < CHW) bch[tid] = b2p[tid];
  __syncthreads();

  for (int idx = tid; idx < EPB * NA_DIM; idx += 512) {
    int e = idx / NA_DIM, c = idx - e * NA_DIM;
    float v = node_attr[(size_t)dsts[e] * NA_DIM + c];
    if (c < 32) x0s[e][c] = v;
    else { int q = c - 32; x1s[e][q % 3][q / 3] = v; }
  }
  if (tid < EPB) atomicAdd(&cnt[srcs[tid]], 1.f);
  __syncthreads();

  { // per-(e,u) derived quantities; 512 = 64*8 exact
    int e = tid >> 3, u = tid & 7;
    float a0 = x1s[e][0][u], a1 = x1s[e][1][u], a2 = x1s[e][2][u];
    float b0 = sh1s[e][0], b1v = sh1s[e][1], b2v = sh1s[e][2];
    dsu[e][u] = a0 * b0 + a1 * b1v + a2 * b2v;
    crs[e][0][u] = a1 * b2v - a2 * b1v;
    crs[e][1][u] = a2 * b0 - a0 * b2v;
    crs[e][2][u] = a0 * b1v - a1 * b0;
  }

  const int ln = tid & 63, wv = tid >> 6;
  short8 af[4][3];
  #pragma unroll
  for (int mt = 0; mt < 4; ++mt)
    #pragma unroll
    for (int s = 0; s < 3; ++s)
      af[mt][s] = *(const short8*)(h + (size_t)(e0 + mt * 16 + (ln & 15)) * HID
                                     + s * 32 + ((ln >> 4) << 3));

  for (int ch = 0; ch < NCH; ++ch) {
    __syncthreads();  // A: prev TP done (ws free), bch[ch] visible
    for (int i = wv; i < NTC; i += 8) {
      int nt = ch * NTC + i;
      f32x4 acc[4];
      #pragma unroll
      for (int mt = 0; mt < 4; ++mt) acc[mt] = (f32x4){0.f, 0.f, 0.f, 0.f};
      #pragma unroll
      for (int s = 0; s < 3; ++s) {
        short8 bfr = *(const short8*)(W2p + ((size_t)(nt * 3 + s) * 64 + ln) * 8);
        #pragma unroll
        for (int mt = 0; mt < 4; ++mt)
          acc[mt] = __builtin_amdgcn_mfma_f32_16x16x32_bf16(af[mt][s], bfr, acc[mt], 0, 0, 0);
      }
      int c16 = ln & 15;
      int l = i * 16 + c16;
      int pc = (l < 128) ? ((l & 96) | ((l + ((l >> 5) << 2)) & 31)) : l;
      float bias = bch[l];
      #pragma unroll
      for (int mt = 0; mt < 4; ++mt)
        #pragma unroll
        for (int r = 0; r < 4; ++r) {
          int e = mt * 16 + ((ln >> 4) << 2) + r;
          ws[e][pc] = f2bf(acc[mt][r] + bias);
        }
    }
    __syncthreads();  // B: ws ready
    {
      const int e = tid >> 3, tt = tid & 7;
      const float s0 = s0s[e];
      const int src = srcs[e];
      if (tt < 4) {
        float sum1 = 0.f;
        #pragma unroll
        for (int u0 = 0; u0 < 32; u0 += 4) {
          int pu = (u0 + (tt << 2)) & 31;
          ushort4v wq = *(const ushort4v*)&ws[e][(tt << 5) + pu];
          float4 xq = *(const float4*)&x0s[e][u0];
          sum1 = fmaf(xq.x, bf2f(wq[0]), sum1);
          sum1 = fmaf(xq.y, bf2f(wq[1]), sum1);
          sum1 = fmaf(xq.z, bf2f(wq[2]), sum1);
          sum1 = fmaf(xq.w, bf2f(wq[3]), sum1);
        }
        float sum2 = 0.f;
        #pragma unroll
        for (int u0 = 0; u0 < 8; u0 += 4) {
          ushort4v wq = *(const ushort4v*)&ws[e][168 + (tt << 3) + u0];
          float4 dq = *(const float4*)&dsu[e][u0];
          sum2 = fmaf(dq.x, bf2f(wq[0]), sum2);
          sum2 = fmaf(dq.y, bf2f(wq[1]), sum2);
          sum2 = fmaf(dq.z, bf2f(wq[2]), sum2);
          sum2 = fmaf(dq.w, bf2f(wq[3]), sum2);
        }
        atomicAdd(&out[(size_t)src * OUT_DIM + 4 * ch + tt],
                  N0f * (s0 * sum1 + INV_S3 * sum2));
      } else if (tt < 7) {
        const int m = tt - 4;
        float sum1 = 0.f;
        #pragma unroll
        for (int u0 = 0; u0 < 32; u0 += 4) {
          ushort4v wq = *(const ushort4v*)&ws[e][128 + u0];
          float4 xq = *(const float4*)&x0s[e][u0];
          sum1 = fmaf(xq.x, bf2f(wq[0]), sum1);
          sum1 = fmaf(xq.y, bf2f(wq[1]), sum1);
          sum1 = fmaf(xq.z, bf2f(wq[2]), sum1);
          sum1 = fmaf(xq.w, bf2f(wq[3]), sum1);
        }
        float sum2 = 0.f;
        #pragma unroll
        for (int u0 = 0; u0 < 8; u0 += 4) {
          ushort4v wq = *(const ushort4v*)&ws[e][160 + u0];
          float4 xq = *(const float4*)&x1s[e][m][u0];
          sum2 = fmaf(xq.x, bf2f(wq[0]), sum2);
          sum2 = fmaf(xq.y, bf2f(wq[1]), sum2);
          sum2 = fmaf(xq.z, bf2f(wq[2]), sum2);
          sum2 = fmaf(xq.w, bf2f(wq[3]), sum2);
        }
        atomicAdd(&out[(size_t)src * OUT_DIM + 32 + ch * 3 + m],
                  N0f * (sh1s[e][m] * sum1 + s0 * sum2));
      } else {
        #pragma unroll
        for (int m = 0; m < 3; ++m) {
          float sum = 0.f;
          #pragma unroll
          for (int u0 = 0; u0 < 8; u0 += 4) {
            ushort4v wq = *(const ushort4v*)&ws[e][200 + u0];
            float4 cq = *(const float4*)&crs[e][m][u0];
            sum = fmaf(cq.x, bf2f(wq[0]), sum);
            sum = fmaf(cq.y, bf2f(wq[1]), sum);
            sum = fmaf(cq.z, bf2f(wq[2]), sum);
            sum = fmaf(cq.w, bf2f(wq[3]), sum);
          }
          atomicAdd(&out[(size_t)src * OUT_DIM + 56 + ch * 3 + m], C_OUT1E * sum);
        }
      }
    }
    if (ch < NCH - 1 && tid < CHW) bch[tid] = b2p[(ch + 1) * CHW + tid];
  }
}

__global__ __launch_bounds__(256) void div_kernel(
    float* __restrict__ out, const float* __restrict__ cnt, int n)
{
  int idx = blockIdx.x * 256 + threadIdx.x;
  if (idx < n) {
    float c = cnt[idx / OUT_DIM];
    out[idx] = out[idx] / fmaxf(c, 1.0f);
  }
}

extern "C" void kernel_launch(void* const* d_in, const int* in_sizes, int n_in,
                              void* d_out, int out_size, void* d_ws, size_t ws_size,
                              hipStream_t stream) {
  const float* node_attr = (const float*)d_in[0];
  const float* edge_attr = (const float*)d_in[1];
  const float* edge_sh   = (const float*)d_in[2];
  const float* W1        = (const float*)d_in[3];
  const float* b1        = (const float*)d_in[4];
  const float* W2        = (const float*)d_in[5];
  const float* b2        = (const float*)d_in[6];
  const int*   edge_src  = (const int*)d_in[7];
  const int*   edge_dst  = (const int*)d_in[8];
  float* out = (float*)d_out;

  const int E = in_sizes[7];
  const int N = in_sizes[0] / NA_DIM;

  float*          cnt = (float*)d_ws;
  unsigned short* W2p = (unsigned short*)((char*)d_ws + (1 << 20));
  unsigned short* W1p = (unsigned short*)((char*)d_ws + (1 << 20) + (512 << 10));
  float*          b2p = (float*)((char*)d_ws + (1 << 20) + (768 << 10));
  unsigned short* hbf = (unsigned short*)((char*)d_ws + (4 << 20));

  zero_kernel<<<(N * OUT_DIM + 255) / 256, 256, 0, stream>>>(out, N * OUT_DIM);
  zero_kernel<<<(N + 255) / 256, 256, 0, stream>>>(cnt, N);

  const int prep_total = NT_TOT * 3 * 64 + 18 * 64 + WNUM;
  prep_kernel<<<(prep_total + 255) / 256, 256, 0, stream>>>(W2, W1, b2, W2p, W1p, b2p);

  gemm1_mfma<<<E / 64, 256, 0, stream>>>(edge_attr, W1p, b1, hbf);
  fused_mfma<<<E / EPB, 512, 0, stream>>>(hbf, W2p, b2p, node_attr, edge_sh,
                                          edge_src, edge_dst, out, cnt);
  div_kernel<<<(N * OUT_DIM + 255) / 256, 256, 0, stream>>>(out, cnt, N * OUT_DIM);
}

// Round 4
// 246.423 us; speedup vs baseline: 13.8451x; 1.8118x over previous
//
#include <hip/hip_runtime.h>

typedef short short8 __attribute__((ext_vector_type(8)));
typedef float f32x4 __attribute__((ext_vector_type(4)));
typedef unsigned short ushort4v __attribute__((ext_vector_type(4)));

#define HID 96
#define WNUM 1664
#define NA_DIM 56
#define OUT_DIM 80
#define EPB 64
#define NT_TOT 104   // 1664/16
#define CHW 208      // cols per chunk
#define NCH 8
#define NTC 13       // n-tiles per chunk

#define N0f 0.158113883f      // 1/sqrt(40)
#define INV_S3 0.5773502692f  // 1/sqrt(3)
#define C_OUT1E 0.25f         // (1/sqrt(2))*(1/sqrt(8))

__device__ __forceinline__ unsigned short f2bf(float x) {
  unsigned u = __builtin_bit_cast(unsigned, x);
  u += 0x7FFFu + ((u >> 16) & 1u);
  return (unsigned short)(u >> 16);
}
__device__ __forceinline__ float bf2f(unsigned short x) {
  unsigned u = ((unsigned)x) << 16;
  return __builtin_bit_cast(float, u);
}

// column permutation: new col J -> original W2 col
__device__ __forceinline__ int perm_col(int J) {
  int c = J / CHW, l = J - (J / CHW) * CHW;
  if (l < 128) { int vp = l >> 5, u = l & 31; return u * 32 + 4 * c + vp; }          // w1
  if (l < 160) { int u = l - 128; return 1024 + u * 8 + c; }                          // w2
  if (l < 168) { int u = l - 160; return 1280 + u * 8 + c; }                          // w3
  if (l < 200) { int q = l - 168; int vp = q >> 3, u = q & 7; return 1344 + u * 32 + 4 * c + vp; } // w4
  { int u = l - 200; return 1600 + u * 8 + c; }                                       // w5
}

__global__ __launch_bounds__(256) void zero_int_kernel(int* __restrict__ p, int n) {
  int i = blockIdx.x * 256 + threadIdx.x;
  if (i < n) p[i] = 0;
}

// ---------------- counting sort of edges by edge_src ----------------
__global__ __launch_bounds__(256) void hist_kernel(
    const int* __restrict__ edge_src, int* __restrict__ hist, int E) {
  int e = blockIdx.x * 256 + threadIdx.x;
  if (e < E) atomicAdd(&hist[edge_src[e]], 1);
}

__global__ __launch_bounds__(256) void scan1_kernel(
    const int* __restrict__ hist, int* __restrict__ excl,
    int* __restrict__ bsum, int n) {
  __shared__ int s[256];
  int t = threadIdx.x, i = blockIdx.x * 256 + t;
  int v = (i < n) ? hist[i] : 0;
  s[t] = v;
  __syncthreads();
  #pragma unroll
  for (int off = 1; off < 256; off <<= 1) {
    int tv = (t >= off) ? s[t - off] : 0;
    __syncthreads();
    s[t] += tv;
    __syncthreads();
  }
  if (i < n) excl[i] = s[t] - v;
  if (t == 255) bsum[blockIdx.x] = s[255];
}

__global__ __launch_bounds__(256) void scan2_kernel(int* __restrict__ bsum, int nb) {
  __shared__ int s[256];
  int t = threadIdx.x;
  int v = (t < nb) ? bsum[t] : 0;
  s[t] = v;
  __syncthreads();
  #pragma unroll
  for (int off = 1; off < 256; off <<= 1) {
    int tv = (t >= off) ? s[t - off] : 0;
    __syncthreads();
    s[t] += tv;
    __syncthreads();
  }
  if (t < nb) bsum[t] = s[t] - v;  // exclusive
}

__global__ __launch_bounds__(256) void scan3_kernel(
    const int* __restrict__ excl, const int* __restrict__ bsum,
    int* __restrict__ start, int* __restrict__ cur, int n) {
  int i = blockIdx.x * 256 + threadIdx.x;
  if (i < n) {
    int v = excl[i] + bsum[blockIdx.x];
    start[i] = v;
    cur[i] = v;
  }
}

__global__ __launch_bounds__(256) void scatter_kernel(
    const int* __restrict__ edge_src, int* __restrict__ cur,
    int* __restrict__ els, int E) {
  int e = blockIdx.x * 256 + threadIdx.x;
  if (e < E) {
    int pos = atomicAdd(&cur[edge_src[e]], 1);
    els[pos] = e;
  }
}

// ---------------- weight prep (bf16 MFMA fragments) ----------------
__global__ __launch_bounds__(256) void prep_kernel(
    const float* __restrict__ W2, const float* __restrict__ W1,
    const float* __restrict__ b2, unsigned short* __restrict__ W2p,
    unsigned short* __restrict__ W1p, float* __restrict__ b2p)
{
  int gid = blockIdx.x * 256 + threadIdx.x;
  const int NW2 = NT_TOT * 3 * 64;
  const int NW1 = 18 * 64;
  if (gid < NW2) {
    int tile = gid >> 6, ln = gid & 63;
    int nt = tile / 3, s = tile - nt * 3;
    int J = nt * 16 + (ln & 15);
    int jo = perm_col(J);
    int kbase = s * 32 + ((ln >> 4) << 3);
    #pragma unroll
    for (int j = 0; j < 8; ++j)
      W2p[(size_t)gid * 8 + j] = f2bf(W2[(kbase + j) * WNUM + jo]);
  } else if (gid < NW2 + NW1) {
    int g = gid - NW2;
    int tile = g >> 6, ln = g & 63;
    int nt = tile / 3, s = tile - nt * 3;
    int col = nt * 16 + (ln & 15);
    int kbase = s * 32 + ((ln >> 4) << 3);
    #pragma unroll
    for (int j = 0; j < 8; ++j)
      W1p[(size_t)g * 8 + j] = f2bf(W1[(kbase + j) * HID + col]);
  } else if (gid < NW2 + NW1 + WNUM) {
    int J = gid - (NW2 + NW1);
    b2p[J] = b2[perm_col(J)];
  }
}

// K1: h = relu(edge_attr @ W1 + b1) in bf16 via MFMA. 64 edges/block, 4 waves.
__global__ __launch_bounds__(256) void gemm1_mfma(
    const float* __restrict__ A, const unsigned short* __restrict__ W1p,
    const float* __restrict__ b1, unsigned short* __restrict__ h)
{
  const int tid = threadIdx.x, ln = tid & 63, wv = tid >> 6;
  const int e0 = blockIdx.x * 64;
  const int row = e0 + wv * 16 + (ln & 15);
  short8 af[3];
  #pragma unroll
  for (int s = 0; s < 3; ++s) {
    const float* p = A + (size_t)row * HID + s * 32 + ((ln >> 4) << 3);
    short8 v;
    #pragma unroll
    for (int j = 0; j < 8; ++j) v[j] = (short)f2bf(p[j]);
    af[s] = v;
  }
  #pragma unroll
  for (int nt = 0; nt < 6; ++nt) {
    f32x4 acc = {0.f, 0.f, 0.f, 0.f};
    #pragma unroll
    for (int s = 0; s < 3; ++s) {
      short8 bfr = *(const short8*)(W1p + ((size_t)(nt * 3 + s) * 64 + ln) * 8);
      acc = __builtin_amdgcn_mfma_f32_16x16x32_bf16(af[s], bfr, acc, 0, 0, 0);
    }
    int col = nt * 16 + (ln & 15);
    float bb = b1[col];
    #pragma unroll
    for (int r = 0; r < 4; ++r) {
      float v = fmaxf(acc[r] + bb, 0.f);
      int er = e0 + wv * 16 + ((ln >> 4) << 2) + r;
      h[(size_t)er * HID + col] = f2bf(v);
    }
  }
}

// K2: fused  w = h@W2+b2 (MFMA, chunked) -> tensor product -> coalesced tp write
__global__ __launch_bounds__(512, 2) void fused_mfma(
    const unsigned short* __restrict__ h, const unsigned short* __restrict__ W2p,
    const float* __restrict__ b2p, const float* __restrict__ node_attr,
    const float* __restrict__ edge_sh, const int* __restrict__ edge_dst,
    float* __restrict__ tpg)
{
  __shared__ unsigned short ws[EPB][212];   // w chunk, bf16, swizzled region0
  __shared__ float tps[EPB * OUT_DIM];      // per-edge tp (each elem written once)
  __shared__ float x0s[EPB][32];
  __shared__ float x1s[EPB][3][8];
  __shared__ float crs[EPB][3][8];
  __shared__ float dsu[EPB][8];
  __shared__ float sh1s[EPB][3];
  __shared__ float s0s[EPB];
  __shared__ int   dsts[EPB];
  __shared__ float bch[CHW];

  const int tid = threadIdx.x;
  const int e0 = blockIdx.x * EPB;

  if (tid < EPB) {
    dsts[tid] = edge_dst[e0 + tid];
    s0s[tid] = edge_sh[(size_t)(e0 + tid) * 4];
  }
  if (tid >= 128 && tid < 128 + EPB * 3) {
    int i = tid - 128, e = i / 3, m = i - e * 3;
    sh1s[e][m] = edge_sh[(size_t)(e0 + e) * 4 + 1 + m];
  }
  if (tid < CHW) bch[tid] = b2p[tid];
  __syncthreads();

  for (int idx = tid; idx < EPB * NA_DIM; idx += 512) {
    int e = idx / NA_DIM, c = idx - e * NA_DIM;
    float v = node_attr[(size_t)dsts[e] * NA_DIM + c];
    if (c < 32) x0s[e][c] = v;
    else { int q = c - 32; x1s[e][q % 3][q / 3] = v; }
  }
  __syncthreads();

  { // per-(e,u) derived quantities; 512 = 64*8 exact
    int e = tid >> 3, u = tid & 7;
    float a0 = x1s[e][0][u], a1 = x1s[e][1][u], a2 = x1s[e][2][u];
    float b0 = sh1s[e][0], b1v = sh1s[e][1], b2v = sh1s[e][2];
    dsu[e][u] = a0 * b0 + a1 * b1v + a2 * b2v;
    crs[e][0][u] = a1 * b2v - a2 * b1v;
    crs[e][1][u] = a2 * b0 - a0 * b2v;
    crs[e][2][u] = a0 * b1v - a1 * b0;
  }

  const int ln = tid & 63, wv = tid >> 6;
  short8 af[4][3];
  #pragma unroll
  for (int mt = 0; mt < 4; ++mt)
    #pragma unroll
    for (int s = 0; s < 3; ++s)
      af[mt][s] = *(const short8*)(h + (size_t)(e0 + mt * 16 + (ln & 15)) * HID
                                     + s * 32 + ((ln >> 4) << 3));

  for (int ch = 0; ch < NCH; ++ch) {
    __syncthreads();  // A: prev TP done (ws free), bch[ch] visible
    for (int i = wv; i < NTC; i += 8) {
      int nt = ch * NTC + i;
      f32x4 acc[4];
      #pragma unroll
      for (int mt = 0; mt < 4; ++mt) acc[mt] = (f32x4){0.f, 0.f, 0.f, 0.f};
      #pragma unroll
      for (int s = 0; s < 3; ++s) {
        short8 bfr = *(const short8*)(W2p + ((size_t)(nt * 3 + s) * 64 + ln) * 8);
        #pragma unroll
        for (int mt = 0; mt < 4; ++mt)
          acc[mt] = __builtin_amdgcn_mfma_f32_16x16x32_bf16(af[mt][s], bfr, acc[mt], 0, 0, 0);
      }
      int c16 = ln & 15;
      int l = i * 16 + c16;
      int pc = (l < 128) ? ((l & 96) | ((l + ((l >> 5) << 2)) & 31)) : l;
      float bias = bch[l];
      #pragma unroll
      for (int mt = 0; mt < 4; ++mt)
        #pragma unroll
        for (int r = 0; r < 4; ++r) {
          int e = mt * 16 + ((ln >> 4) << 2) + r;
          ws[e][pc] = f2bf(acc[mt][r] + bias);
        }
    }
    __syncthreads();  // B: ws ready
    {
      const int e = tid >> 3, tt = tid & 7;
      const float s0 = s0s[e];
      if (tt < 4) {
        float sum1 = 0.f;
        #pragma unroll
        for (int u0 = 0; u0 < 32; u0 += 4) {
          int pu = (u0 + (tt << 2)) & 31;       // swizzled LDS col of logical u0
          ushort4v wq = *(const ushort4v*)&ws[e][(tt << 5) + pu];
          float4 xq = *(const float4*)&x0s[e][u0];  // logical u0..u0+3
          sum1 = fmaf(xq.x, bf2f(wq[0]), sum1);
          sum1 = fmaf(xq.y, bf2f(wq[1]), sum1);
          sum1 = fmaf(xq.z, bf2f(wq[2]), sum1);
          sum1 = fmaf(xq.w, bf2f(wq[3]), sum1);
        }
        float sum2 = 0.f;
        #pragma unroll
        for (int u0 = 0; u0 < 8; u0 += 4) {
          ushort4v wq = *(const ushort4v*)&ws[e][168 + (tt << 3) + u0];
          float4 dq = *(const float4*)&dsu[e][u0];
          sum2 = fmaf(dq.x, bf2f(wq[0]), sum2);
          sum2 = fmaf(dq.y, bf2f(wq[1]), sum2);
          sum2 = fmaf(dq.z, bf2f(wq[2]), sum2);
          sum2 = fmaf(dq.w, bf2f(wq[3]), sum2);
        }
        tps[e * OUT_DIM + 4 * ch + tt] = N0f * (s0 * sum1 + INV_S3 * sum2);
      } else if (tt < 7) {
        const int m = tt - 4;
        float sum1 = 0.f;
        #pragma unroll
        for (int u0 = 0; u0 < 32; u0 += 4) {
          ushort4v wq = *(const ushort4v*)&ws[e][128 + u0];
          float4 xq = *(const float4*)&x0s[e][u0];
          sum1 = fmaf(xq.x, bf2f(wq[0]), sum1);
          sum1 = fmaf(xq.y, bf2f(wq[1]), sum1);
          sum1 = fmaf(xq.z, bf2f(wq[2]), sum1);
          sum1 = fmaf(xq.w, bf2f(wq[3]), sum1);
        }
        float sum2 = 0.f;
        #pragma unroll
        for (int u0 = 0; u0 < 8; u0 += 4) {
          ushort4v wq = *(const ushort4v*)&ws[e][160 + u0];
          float4 xq = *(const float4*)&x1s[e][m][u0];
          sum2 = fmaf(xq.x, bf2f(wq[0]), sum2);
          sum2 = fmaf(xq.y, bf2f(wq[1]), sum2);
          sum2 = fmaf(xq.z, bf2f(wq[2]), sum2);
          sum2 = fmaf(xq.w, bf2f(wq[3]), sum2);
        }
        tps[e * OUT_DIM + 32 + ch * 3 + m] = N0f * (sh1s[e][m] * sum1 + s0 * sum2);
      } else {
        #pragma unroll
        for (int m = 0; m < 3; ++m) {
          float sum = 0.f;
          #pragma unroll
          for (int u0 = 0; u0 < 8; u0 += 4) {
            ushort4v wq = *(const ushort4v*)&ws[e][200 + u0];
            float4 cq = *(const float4*)&crs[e][m][u0];
            sum = fmaf(cq.x, bf2f(wq[0]), sum);
            sum = fmaf(cq.y, bf2f(wq[1]), sum);
            sum = fmaf(cq.z, bf2f(wq[2]), sum);
            sum = fmaf(cq.w, bf2f(wq[3]), sum);
          }
          tps[e * OUT_DIM + 56 + ch * 3 + m] = C_OUT1E * sum;
        }
      }
    }
    if (ch < NCH - 1 && tid < CHW) bch[tid] = b2p[(ch + 1) * CHW + tid];
  }

  __syncthreads();  // tps complete
  #pragma unroll
  for (int k = 0; k < EPB * OUT_DIM / 512; ++k) {
    int idx = tid + k * 512;
    tpg[(size_t)e0 * OUT_DIM + idx] = tps[idx];
  }
}

// K3: per-node mean over sorted edge lists (no atomics)
__global__ __launch_bounds__(256) void gather_kernel(
    const float* __restrict__ tp, const int* __restrict__ els,
    const int* __restrict__ start, const int* __restrict__ hist,
    float* __restrict__ out, int total)
{
  int idx = blockIdx.x * 256 + threadIdx.x;
  if (idx >= total) return;
  int node = idx / OUT_DIM, o = idx - node * OUT_DIM;
  int s = start[node], c = hist[node];
  float sum = 0.f;
  for (int i = 0; i < c; ++i)
    sum += tp[(size_t)els[s + i] * OUT_DIM + o];
  out[idx] = sum / (float)(c > 0 ? c : 1);
}

extern "C" void kernel_launch(void* const* d_in, const int* in_sizes, int n_in,
                              void* d_out, int out_size, void* d_ws, size_t ws_size,
                              hipStream_t stream) {
  const float* node_attr = (const float*)d_in[0];
  const float* edge_attr = (const float*)d_in[1];
  const float* edge_sh   = (const float*)d_in[2];
  const float* W1        = (const float*)d_in[3];
  const float* b1        = (const float*)d_in[4];
  const float* W2        = (const float*)d_in[5];
  const float* b2        = (const float*)d_in[6];
  const int*   edge_src  = (const int*)d_in[7];
  const int*   edge_dst  = (const int*)d_in[8];
  float* out = (float*)d_out;

  const int E = in_sizes[7];
  const int N = in_sizes[0] / NA_DIM;

  char* wsb = (char*)d_ws;
  int*   hist  = (int*)(wsb + 0x000000);          // 40000 ints
  int*   excl  = (int*)(wsb + 0x040000);
  int*   start = (int*)(wsb + 0x080000);
  int*   cur   = (int*)(wsb + 0x0C0000);
  int*   bsum  = (int*)(wsb + 0x100000);          // 256 ints
  int*   els   = (int*)(wsb + 0x110000);          // 120000 ints
  unsigned short* W2p = (unsigned short*)(wsb + 0x200000);   // 320 KB
  unsigned short* W1p = (unsigned short*)(wsb + 0x280000);
  float*          b2p = (float*)(wsb + 0x2C0000);
  unsigned short* hbf = (unsigned short*)(wsb + 0x300000);   // 23 MB
  float*          tpg = (float*)(wsb + 0x1C00000);           // 38.4 MB

  const int NB = (N + 255) / 256;  // 157

  zero_int_kernel<<<NB, 256, 0, stream>>>(hist, N);
  hist_kernel<<<(E + 255) / 256, 256, 0, stream>>>(edge_src, hist, E);
  scan1_kernel<<<NB, 256, 0, stream>>>(hist, excl, bsum, N);
  scan2_kernel<<<1, 256, 0, stream>>>(bsum, NB);
  scan3_kernel<<<NB, 256, 0, stream>>>(excl, bsum, start, cur, N);
  scatter_kernel<<<(E + 255) / 256, 256, 0, stream>>>(edge_src, cur, els, E);

  const int prep_total = NT_TOT * 3 * 64 + 18 * 64 + WNUM;
  prep_kernel<<<(prep_total + 255) / 256, 256, 0, stream>>>(W2, W1, b2, W2p, W1p, b2p);

  gemm1_mfma<<<E / 64, 256, 0, stream>>>(edge_attr, W1p, b1, hbf);
  fused_mfma<<<E / EPB, 512, 0, stream>>>(hbf, W2p, b2p, node_attr, edge_sh,
                                          edge_dst, tpg);
  gather_kernel<<<(N * OUT_DIM + 255) / 256, 256, 0, stream>>>(
      tpg, els, start, hist, out, N * OUT_DIM);
}

// Round 5
// 193.671 us; speedup vs baseline: 17.6161x; 1.2724x over previous
//
#include <hip/hip_runtime.h>

typedef short short8 __attribute__((ext_vector_type(8)));
typedef float f32x4 __attribute__((ext_vector_type(4)));
typedef unsigned short ushort4v __attribute__((ext_vector_type(4)));

#define HID 96
#define WNUM 1664
#define NA_DIM 56
#define OUT_DIM 80
#define EPB 64
#define NT_TOT 104   // 1664/16
#define CHW 208      // cols per chunk
#define NCH 8
#define NTC 13       // n-tiles per chunk

#define N0f 0.158113883f      // 1/sqrt(40)
#define INV_S3 0.5773502692f  // 1/sqrt(3)
#define C_OUT1E 0.25f         // (1/sqrt(2))*(1/sqrt(8))

__device__ __forceinline__ unsigned short f2bf(float x) {
  unsigned u = __builtin_bit_cast(unsigned, x);
  u += 0x7FFFu + ((u >> 16) & 1u);
  return (unsigned short)(u >> 16);
}
__device__ __forceinline__ float bf2f(unsigned short x) {
  unsigned u = ((unsigned)x) << 16;
  return __builtin_bit_cast(float, u);
}

// column permutation: new col J -> original W2 col
__device__ __forceinline__ int perm_col(int J) {
  int c = J / CHW, l = J - (J / CHW) * CHW;
  if (l < 128) { int vp = l >> 5, u = l & 31; return u * 32 + 4 * c + vp; }          // w1
  if (l < 160) { int u = l - 128; return 1024 + u * 8 + c; }                          // w2
  if (l < 168) { int u = l - 160; return 1280 + u * 8 + c; }                          // w3
  if (l < 200) { int q = l - 168; int vp = q >> 3, u = q & 7; return 1344 + u * 32 + 4 * c + vp; } // w4
  { int u = l - 200; return 1600 + u * 8 + c; }                                       // w5
}

__global__ __launch_bounds__(256) void zero_int_kernel(int* __restrict__ p, int n) {
  int i = blockIdx.x * 256 + threadIdx.x;
  if (i < n) p[i] = 0;
}

// ---------------- counting sort of edges by edge_src ----------------
__global__ __launch_bounds__(256) void hist_kernel(
    const int* __restrict__ edge_src, int* __restrict__ hist, int E) {
  int e = blockIdx.x * 256 + threadIdx.x;
  if (e < E) atomicAdd(&hist[edge_src[e]], 1);
}

__global__ __launch_bounds__(256) void scan1_kernel(
    const int* __restrict__ hist, int* __restrict__ excl,
    int* __restrict__ bsum, int n) {
  __shared__ int s[256];
  int t = threadIdx.x, i = blockIdx.x * 256 + t;
  int v = (i < n) ? hist[i] : 0;
  s[t] = v;
  __syncthreads();
  #pragma unroll
  for (int off = 1; off < 256; off <<= 1) {
    int tv = (t >= off) ? s[t - off] : 0;
    __syncthreads();
    s[t] += tv;
    __syncthreads();
  }
  if (i < n) excl[i] = s[t] - v;
  if (t == 255) bsum[blockIdx.x] = s[255];
}

__global__ __launch_bounds__(256) void scan2_kernel(int* __restrict__ bsum, int nb) {
  __shared__ int s[256];
  int t = threadIdx.x;
  int v = (t < nb) ? bsum[t] : 0;
  s[t] = v;
  __syncthreads();
  #pragma unroll
  for (int off = 1; off < 256; off <<= 1) {
    int tv = (t >= off) ? s[t - off] : 0;
    __syncthreads();
    s[t] += tv;
    __syncthreads();
  }
  if (t < nb) bsum[t] = s[t] - v;  // exclusive
}

__global__ __launch_bounds__(256) void scan3_kernel(
    const int* __restrict__ excl, const int* __restrict__ bsum,
    int* __restrict__ start, int* __restrict__ cur, int n) {
  int i = blockIdx.x * 256 + threadIdx.x;
  if (i < n) {
    int v = excl[i] + bsum[blockIdx.x];
    start[i] = v;
    cur[i] = v;
  }
}

__global__ __launch_bounds__(256) void scatter_kernel(
    const int* __restrict__ edge_src, int* __restrict__ cur,
    int* __restrict__ els, int E) {
  int e = blockIdx.x * 256 + threadIdx.x;
  if (e < E) {
    int pos = atomicAdd(&cur[edge_src[e]], 1);
    els[pos] = e;
  }
}

// ---------------- weight prep (bf16 MFMA fragments) ----------------
__global__ __launch_bounds__(256) void prep_kernel(
    const float* __restrict__ W2, const float* __restrict__ W1,
    const float* __restrict__ b2, unsigned short* __restrict__ W2p,
    unsigned short* __restrict__ W1p, float* __restrict__ b2p)
{
  int gid = blockIdx.x * 256 + threadIdx.x;
  const int NW2 = NT_TOT * 3 * 64;
  const int NW1 = 18 * 64;
  if (gid < NW2) {
    int tile = gid >> 6, ln = gid & 63;
    int nt = tile / 3, s = tile - nt * 3;
    int J = nt * 16 + (ln & 15);
    int jo = perm_col(J);
    int kbase = s * 32 + ((ln >> 4) << 3);
    #pragma unroll
    for (int j = 0; j < 8; ++j)
      W2p[(size_t)gid * 8 + j] = f2bf(W2[(kbase + j) * WNUM + jo]);
  } else if (gid < NW2 + NW1) {
    int g = gid - NW2;
    int tile = g >> 6, ln = g & 63;
    int nt = tile / 3, s = tile - nt * 3;
    int col = nt * 16 + (ln & 15);
    int kbase = s * 32 + ((ln >> 4) << 3);
    #pragma unroll
    for (int j = 0; j < 8; ++j)
      W1p[(size_t)g * 8 + j] = f2bf(W1[(kbase + j) * HID + col]);
  } else if (gid < NW2 + NW1 + WNUM) {
    int J = gid - (NW2 + NW1);
    b2p[J] = b2[perm_col(J)];
  }
}

// K1: h = relu(edge_attr @ W1 + b1) in bf16 via MFMA. 64 edges/block, 4 waves.
__global__ __launch_bounds__(256) void gemm1_mfma(
    const float* __restrict__ A, const unsigned short* __restrict__ W1p,
    const float* __restrict__ b1, unsigned short* __restrict__ h)
{
  const int tid = threadIdx.x, ln = tid & 63, wv = tid >> 6;
  const int e0 = blockIdx.x * 64;
  const int row = e0 + wv * 16 + (ln & 15);
  short8 af[3];
  #pragma unroll
  for (int s = 0; s < 3; ++s) {
    const float* p = A + (size_t)row * HID + s * 32 + ((ln >> 4) << 3);
    short8 v;
    #pragma unroll
    for (int j = 0; j < 8; ++j) v[j] = (short)f2bf(p[j]);
    af[s] = v;
  }
  #pragma unroll
  for (int nt = 0; nt < 6; ++nt) {
    f32x4 acc = {0.f, 0.f, 0.f, 0.f};
    #pragma unroll
    for (int s = 0; s < 3; ++s) {
      short8 bfr = *(const short8*)(W1p + ((size_t)(nt * 3 + s) * 64 + ln) * 8);
      acc = __builtin_amdgcn_mfma_f32_16x16x32_bf16(af[s], bfr, acc, 0, 0, 0);
    }
    int col = nt * 16 + (ln & 15);
    float bb = b1[col];
    #pragma unroll
    for (int r = 0; r < 4; ++r) {
      float v = fmaxf(acc[r] + bb, 0.f);
      int er = e0 + wv * 16 + ((ln >> 4) << 2) + r;
      h[(size_t)er * HID + col] = f2bf(v);
    }
  }
}

// K2: fused  w = h@W2+b2 (MFMA, double-buffered) -> tensor product -> direct store
__global__ __launch_bounds__(512, 4) void fused_mfma(
    const unsigned short* __restrict__ h, const unsigned short* __restrict__ W2p,
    const float* __restrict__ b2p, const float* __restrict__ node_attr,
    const float* __restrict__ edge_sh, const int* __restrict__ edge_dst,
    float* __restrict__ tpg)
{
  __shared__ __align__(16) unsigned short ws[2][EPB][212];  // double-buffered w chunk
  __shared__ float x0s[EPB][32];
  __shared__ float x1s[EPB][3][8];
  __shared__ float crs[EPB][3][8];
  __shared__ float dsu[EPB][8];
  __shared__ float sh1s[EPB][3];
  __shared__ float s0s[EPB];
  __shared__ int   dsts[EPB];

  const int tid = threadIdx.x;
  const int e0 = blockIdx.x * EPB;

  if (tid < EPB) {
    dsts[tid] = edge_dst[e0 + tid];
    s0s[tid] = edge_sh[(size_t)(e0 + tid) * 4];
  }
  if (tid >= 128 && tid < 128 + EPB * 3) {
    int i = tid - 128, e = i / 3, m = i - e * 3;
    sh1s[e][m] = edge_sh[(size_t)(e0 + e) * 4 + 1 + m];
  }
  __syncthreads();

  for (int idx = tid; idx < EPB * NA_DIM; idx += 512) {
    int e = idx / NA_DIM, c = idx - e * NA_DIM;
    float v = node_attr[(size_t)dsts[e] * NA_DIM + c];
    if (c < 32) x0s[e][c] = v;
    else { int q = c - 32; x1s[e][q % 3][q / 3] = v; }
  }
  __syncthreads();

  { // per-(e,u) derived quantities; 512 = 64*8 exact
    int e = tid >> 3, u = tid & 7;
    float a0 = x1s[e][0][u], a1 = x1s[e][1][u], a2 = x1s[e][2][u];
    float b0 = sh1s[e][0], b1v = sh1s[e][1], b2v = sh1s[e][2];
    dsu[e][u] = a0 * b0 + a1 * b1v + a2 * b2v;
    crs[e][0][u] = a1 * b2v - a2 * b1v;
    crs[e][1][u] = a2 * b0 - a0 * b2v;
    crs[e][2][u] = a0 * b1v - a1 * b0;
  }

  const int ln = tid & 63, wv = tid >> 6;
  short8 af[4][3];
  #pragma unroll
  for (int mt = 0; mt < 4; ++mt)
    #pragma unroll
    for (int s = 0; s < 3; ++s)
      af[mt][s] = *(const short8*)(h + (size_t)(e0 + mt * 16 + (ln & 15)) * HID
                                     + s * 32 + ((ln >> 4) << 3));

  // GEMM one 208-col chunk cc into LDS buffer wsd (MFMA + bias, swizzled w1 region)
  auto compute_chunk = [&](int cc, unsigned short (*wsd)[212]) {
    for (int i = wv; i < NTC; i += 8) {
      int nt = cc * NTC + i;
      f32x4 acc[4];
      #pragma unroll
      for (int mt = 0; mt < 4; ++mt) acc[mt] = (f32x4){0.f, 0.f, 0.f, 0.f};
      #pragma unroll
      for (int s = 0; s < 3; ++s) {
        short8 bfr = *(const short8*)(W2p + ((size_t)(nt * 3 + s) * 64 + ln) * 8);
        #pragma unroll
        for (int mt = 0; mt < 4; ++mt)
          acc[mt] = __builtin_amdgcn_mfma_f32_16x16x32_bf16(af[mt][s], bfr, acc[mt], 0, 0, 0);
      }
      int c16 = ln & 15;
      int l = i * 16 + c16;
      int pc = (l < 128) ? ((l & 96) | ((l + ((l >> 5) << 2)) & 31)) : l;
      float bias = b2p[cc * CHW + l];
      #pragma unroll
      for (int mt = 0; mt < 4; ++mt)
        #pragma unroll
        for (int r = 0; r < 4; ++r) {
          int e = mt * 16 + ((ln >> 4) << 2) + r;
          wsd[e][pc] = f2bf(acc[mt][r] + bias);
        }
    }
  };

  compute_chunk(0, ws[0]);
  __syncthreads();

  const int e = tid >> 3, tt = tid & 7;
  const float s0 = s0s[e];
  float* tpr = tpg + (size_t)(e0 + e) * OUT_DIM;

  for (int ch = 0; ch < NCH; ++ch) {
    if (ch < NCH - 1) compute_chunk(ch + 1, ws[(ch + 1) & 1]);  // overlaps TP below

    const unsigned short (*wsr)[212] = ws[ch & 1];
    if (tt < 4) {
      float sa = 0.f, sb = 0.f;
      #pragma unroll
      for (int u0 = 0; u0 < 32; u0 += 8) {
        int pu  = (u0 + (tt << 2)) & 31;       // swizzled LDS col of logical u0
        int pu2 = (u0 + 4 + (tt << 2)) & 31;
        ushort4v wq  = *(const ushort4v*)&wsr[e][(tt << 5) + pu];
        ushort4v wq2 = *(const ushort4v*)&wsr[e][(tt << 5) + pu2];
        float4 xq  = *(const float4*)&x0s[e][u0];
        float4 xq2 = *(const float4*)&x0s[e][u0 + 4];
        sa = fmaf(xq.x, bf2f(wq[0]), sa);
        sa = fmaf(xq.y, bf2f(wq[1]), sa);
        sa = fmaf(xq.z, bf2f(wq[2]), sa);
        sa = fmaf(xq.w, bf2f(wq[3]), sa);
        sb = fmaf(xq2.x, bf2f(wq2[0]), sb);
        sb = fmaf(xq2.y, bf2f(wq2[1]), sb);
        sb = fmaf(xq2.z, bf2f(wq2[2]), sb);
        sb = fmaf(xq2.w, bf2f(wq2[3]), sb);
      }
      float sum2 = 0.f;
      #pragma unroll
      for (int u0 = 0; u0 < 8; u0 += 4) {
        ushort4v wq = *(const ushort4v*)&wsr[e][168 + (tt << 3) + u0];
        float4 dq = *(const float4*)&dsu[e][u0];
        sum2 = fmaf(dq.x, bf2f(wq[0]), sum2);
        sum2 = fmaf(dq.y, bf2f(wq[1]), sum2);
        sum2 = fmaf(dq.z, bf2f(wq[2]), sum2);
        sum2 = fmaf(dq.w, bf2f(wq[3]), sum2);
      }
      tpr[4 * ch + tt] = N0f * (s0 * (sa + sb) + INV_S3 * sum2);
    } else if (tt < 7) {
      const int m = tt - 4;
      float sa = 0.f, sb = 0.f;
      #pragma unroll
      for (int u0 = 0; u0 < 32; u0 += 8) {
        ushort4v wq  = *(const ushort4v*)&wsr[e][128 + u0];
        ushort4v wq2 = *(const ushort4v*)&wsr[e][128 + u0 + 4];
        float4 xq  = *(const float4*)&x0s[e][u0];
        float4 xq2 = *(const float4*)&x0s[e][u0 + 4];
        sa = fmaf(xq.x, bf2f(wq[0]), sa);
        sa = fmaf(xq.y, bf2f(wq[1]), sa);
        sa = fmaf(xq.z, bf2f(wq[2]), sa);
        sa = fmaf(xq.w, bf2f(wq[3]), sa);
        sb = fmaf(xq2.x, bf2f(wq2[0]), sb);
        sb = fmaf(xq2.y, bf2f(wq2[1]), sb);
        sb = fmaf(xq2.z, bf2f(wq2[2]), sb);
        sb = fmaf(xq2.w, bf2f(wq2[3]), sb);
      }
      float sum2 = 0.f;
      #pragma unroll
      for (int u0 = 0; u0 < 8; u0 += 4) {
        ushort4v wq = *(const ushort4v*)&wsr[e][160 + u0];
        float4 xq = *(const float4*)&x1s[e][m][u0];
        sum2 = fmaf(xq.x, bf2f(wq[0]), sum2);
        sum2 = fmaf(xq.y, bf2f(wq[1]), sum2);
        sum2 = fmaf(xq.z, bf2f(wq[2]), sum2);
        sum2 = fmaf(xq.w, bf2f(wq[3]), sum2);
      }
      tpr[32 + ch * 3 + m] = N0f * (sh1s[e][m] * (sa + sb) + s0 * sum2);
    } else {
      #pragma unroll
      for (int m = 0; m < 3; ++m) {
        float sum = 0.f;
        #pragma unroll
        for (int u0 = 0; u0 < 8; u0 += 4) {
          ushort4v wq = *(const ushort4v*)&wsr[e][200 + u0];
          float4 cq = *(const float4*)&crs[e][m][u0];
          sum = fmaf(cq.x, bf2f(wq[0]), sum);
          sum = fmaf(cq.y, bf2f(wq[1]), sum);
          sum = fmaf(cq.z, bf2f(wq[2]), sum);
          sum = fmaf(cq.w, bf2f(wq[3]), sum);
        }
        tpr[56 + ch * 3 + m] = C_OUT1E * sum;
      }
    }
    __syncthreads();  // ws[(ch+1)&1] complete, ws[ch&1] free for reuse
  }
}

// K3: per-node mean over sorted edge lists (no atomics)
__global__ __launch_bounds__(256) void gather_kernel(
    const float* __restrict__ tp, const int* __restrict__ els,
    const int* __restrict__ start, const int* __restrict__ hist,
    float* __restrict__ out, int total)
{
  int idx = blockIdx.x * 256 + threadIdx.x;
  if (idx >= total) return;
  int node = idx / OUT_DIM, o = idx - node * OUT_DIM;
  int s = start[node], c = hist[node];
  float sum = 0.f;
  for (int i = 0; i < c; ++i)
    sum += tp[(size_t)els[s + i] * OUT_DIM + o];
  out[idx] = sum / (float)(c > 0 ? c : 1);
}

extern "C" void kernel_launch(void* const* d_in, const int* in_sizes, int n_in,
                              void* d_out, int out_size, void* d_ws, size_t ws_size,
                              hipStream_t stream) {
  const float* node_attr = (const float*)d_in[0];
  const float* edge_attr = (const float*)d_in[1];
  const float* edge_sh   = (const float*)d_in[2];
  const float* W1        = (const float*)d_in[3];
  const float* b1        = (const float*)d_in[4];
  const float* W2        = (const float*)d_in[5];
  const float* b2        = (const float*)d_in[6];
  const int*   edge_src  = (const int*)d_in[7];
  const int*   edge_dst  = (const int*)d_in[8];
  float* out = (float*)d_out;

  const int E = in_sizes[7];
  const int N = in_sizes[0] / NA_DIM;

  char* wsb = (char*)d_ws;
  int*   hist  = (int*)(wsb + 0x000000);          // 40000 ints
  int*   excl  = (int*)(wsb + 0x040000);
  int*   start = (int*)(wsb + 0x080000);
  int*   cur   = (int*)(wsb + 0x0C0000);
  int*   bsum  = (int*)(wsb + 0x100000);          // 256 ints
  int*   els   = (int*)(wsb + 0x110000);          // 120000 ints
  unsigned short* W2p = (unsigned short*)(wsb + 0x200000);   // 320 KB
  unsigned short* W1p = (unsigned short*)(wsb + 0x280000);
  float*          b2p = (float*)(wsb + 0x2C0000);
  unsigned short* hbf = (unsigned short*)(wsb + 0x300000);   // 23 MB
  float*          tpg = (float*)(wsb + 0x1C00000);           // 38.4 MB

  const int NB = (N + 255) / 256;  // 157

  zero_int_kernel<<<NB, 256, 0, stream>>>(hist, N);
  hist_kernel<<<(E + 255) / 256, 256, 0, stream>>>(edge_src, hist, E);
  scan1_kernel<<<NB, 256, 0, stream>>>(hist, excl, bsum, N);
  scan2_kernel<<<1, 256, 0, stream>>>(bsum, NB);
  scan3_kernel<<<NB, 256, 0, stream>>>(excl, bsum, start, cur, N);
  scatter_kernel<<<(E + 255) / 256, 256, 0, stream>>>(edge_src, cur, els, E);

  const int prep_total = NT_TOT * 3 * 64 + 18 * 64 + WNUM;
  prep_kernel<<<(prep_total + 255) / 256, 256, 0, stream>>>(W2, W1, b2, W2p, W1p, b2p);

  gemm1_mfma<<<E / 64, 256, 0, stream>>>(edge_attr, W1p, b1, hbf);
  fused_mfma<<<E / EPB, 512, 0, stream>>>(hbf, W2p, b2p, node_attr, edge_sh,
                                          edge_dst, tpg);
  gather_kernel<<<(N * OUT_DIM + 255) / 256, 256, 0, stream>>>(
      tpg, els, start, hist, out, N * OUT_DIM);
}